// Round 1
// baseline (108.799 us; speedup 1.0000x reference)
//
#include <hip/hip_runtime.h>

// Problem constants (match reference)
#define BB 8192
#define SS 7
#define EE 2048
#define EV (EE / 4)   // float4 groups per row = 512

// fast tanh: 1 - 2/(exp(2x)+1), ~1e-6 abs error, threshold is 2e-2.
// __expf -> v_exp_f32 (native), rcpf -> v_rcp_f32 (1 instr, ~22-bit).
__device__ __forceinline__ float fast_tanh(float x) {
    float t = fminf(fmaxf(x, -15.f), 15.f);
    float e = __expf(2.f * t);
    return 1.f - 2.f * __builtin_amdgcn_rcpf(e + 1.f);
}

__global__ __launch_bounds__(256) void CSM_62216896250027_kernel(
    const float* __restrict__ X,
    const float* __restrict__ c1,   // (2, E)
    const float* __restrict__ c2,   // (2, E)
    const float* __restrict__ c3,   // (3, E)
    const float* __restrict__ c4,   // (3, E)
    float* __restrict__ out)        // (B, E)
{
    const int t  = blockIdx.x * blockDim.x + threadIdx.x;   // one (b, e4) per thread
    const int b  = t / EV;
    const int ev = t - b * EV;
    if (b >= BB) return;

    const float4* Xv = (const float4*)X;

    // ---- load 7 sentence positions, 4 channels each (coalesced 16B/lane) ----
    float xx[SS][4];
    #pragma unroll
    for (int s = 0; s < SS; ++s) {
        float4 v = Xv[(b * SS + s) * EV + ev];
        xx[s][0] = v.x; xx[s][1] = v.y; xx[s][2] = v.z; xx[s][3] = v.w;
    }

    // ---- load per-channel weights (L1/L2 broadcast hits) ----
    float k1[2][4], k2[2][4], k3[3][4], k4[3][4];
    #pragma unroll
    for (int i = 0; i < 2; ++i) {
        float4 v = ((const float4*)c1)[i * EV + ev];
        k1[i][0] = v.x; k1[i][1] = v.y; k1[i][2] = v.z; k1[i][3] = v.w;
        float4 w = ((const float4*)c2)[i * EV + ev];
        k2[i][0] = w.x; k2[i][1] = w.y; k2[i][2] = w.z; k2[i][3] = w.w;
    }
    #pragma unroll
    for (int i = 0; i < 3; ++i) {
        float4 v = ((const float4*)c3)[i * EV + ev];
        k3[i][0] = v.x; k3[i][1] = v.y; k3[i][2] = v.z; k3[i][3] = v.w;
        float4 w = ((const float4*)c4)[i * EV + ev];
        k4[i][0] = w.x; k4[i][1] = w.y; k4[i][2] = w.z; k4[i][3] = w.w;
    }

    // ---- chain: 7 -> 6 -> 5 -> 3 -> 1, per channel j ----
    float4 r;
    float res[4];
    #pragma unroll
    for (int j = 0; j < 4; ++j) {
        float y1[6];
        #pragma unroll
        for (int s = 0; s < 6; ++s)
            y1[s] = fast_tanh(fmaf(xx[s][j], k1[0][j], xx[s + 1][j] * k1[1][j]));
        float y2[5];
        #pragma unroll
        for (int s = 0; s < 5; ++s)
            y2[s] = fast_tanh(fmaf(y1[s], k2[0][j], y1[s + 1] * k2[1][j]));
        float y3[3];
        #pragma unroll
        for (int s = 0; s < 3; ++s)
            y3[s] = fast_tanh(fmaf(y2[s], k3[0][j],
                              fmaf(y2[s + 1], k3[1][j], y2[s + 2] * k3[2][j])));
        res[j] = fast_tanh(fmaf(y3[0], k4[0][j],
                           fmaf(y3[1], k4[1][j], y3[2] * k4[2][j])));
    }
    r.x = res[0]; r.y = res[1]; r.z = res[2]; r.w = res[3];

    ((float4*)out)[b * EV + ev] = r;
}

extern "C" void kernel_launch(void* const* d_in, const int* in_sizes, int n_in,
                              void* d_out, int out_size, void* d_ws, size_t ws_size,
                              hipStream_t stream) {
    const float* X  = (const float*)d_in[0];
    const float* c1 = (const float*)d_in[1];
    const float* c2 = (const float*)d_in[2];
    const float* c3 = (const float*)d_in[3];
    const float* c4 = (const float*)d_in[4];
    float* out = (float*)d_out;

    const int total_threads = BB * EV;           // 4,194,304
    const int block = 256;
    const int grid = total_threads / block;      // 16384
    CSM_62216896250027_kernel<<<grid, block, 0, stream>>>(X, c1, c2, c3, c4, out);
}